// Round 9
// baseline (216.926 us; speedup 1.0000x reference)
//
#include <hip/hip_runtime.h>

typedef __bf16 bf16x8 __attribute__((ext_vector_type(8)));
typedef float floatx4 __attribute__((ext_vector_type(4)));
typedef float floatx16 __attribute__((ext_vector_type(16)));
typedef unsigned int u32;

#define BB 4
#define CC 256
#define NN 4096

__device__ __forceinline__ unsigned short f2bf(float f) {
  union { float f; unsigned u; } v; v.f = f;
  unsigned r = v.u + 0x7fffu + ((v.u >> 16) & 1u);
  return (unsigned short)(r >> 16);
}

__device__ __forceinline__ float bf2f(unsigned short s) {
  union { unsigned u; float f; } v; v.u = ((u32)s) << 16;
  return v.f;
}

__device__ __forceinline__ void async16(const void* g, void* l) {
  __builtin_amdgcn_global_load_lds((const __attribute__((address_space(1))) u32*)g,
                                   (__attribute__((address_space(3))) u32*)l, 16, 0, 0);
}

__device__ __forceinline__ u32 fbits(float f) {
  union { float f; u32 u; } v; v.f = f; return v.u;
}

// ------- GroupNorm stats (blocks 1024..1151) + weight bf16 convert (blocks 0..1023) ----------
__global__ __launch_bounds__(256) void gn_stats_wconv(const float* __restrict__ x, float* __restrict__ mr,
                                                      const float* __restrict__ wqkv, const float* __restrict__ wproj,
                                                      unsigned short* __restrict__ wq_bf, unsigned short* __restrict__ wp_bf) {
  if (blockIdx.x < 1024) {
    int i = blockIdx.x * 256 + threadIdx.x;
    if (i < 196608) {
      float v = wqkv[i];
      if (i < 65536) v *= 0.090168440055560213f;  // log2(e)/16
      wq_bf[i] = f2bf(v);
    } else {
      int j = i - 196608;
      wp_bf[j] = f2bf(wproj[j]);
    }
    return;
  }
  int bg = blockIdx.x - 1024;
  const float* p = x + (size_t)bg * 32768;
  int t = threadIdx.x;
  float s = 0.f, q = 0.f;
#pragma unroll
  for (int it = 0; it < 32; ++it) {
    float4 v = *(const float4*)(p + it * 1024 + t * 4);
    s += v.x + v.y + v.z + v.w;
    q += v.x * v.x + v.y * v.y + v.z * v.z + v.w * v.w;
  }
#pragma unroll
  for (int off = 1; off < 64; off <<= 1) {
    s += __shfl_xor(s, off, 64);
    q += __shfl_xor(q, off, 64);
  }
  __shared__ float red[8];
  int w = t >> 6;
  if ((t & 63) == 0) { red[w] = s; red[4 + w] = q; }
  __syncthreads();
  if (t == 0) {
    float S = red[0] + red[1] + red[2] + red[3];
    float Q = red[4] + red[5] + red[6] + red[7];
    float mean = S * (1.f / 32768.f);
    float var = Q * (1.f / 32768.f) - mean * mean;
    mr[bg] = mean;
    mr[128 + bg] = rsqrtf(var + 1e-5f);
  }
}

// ---------------- normalize + transpose to normed[b][n][c] bf16 ----------------
__global__ __launch_bounds__(256) void gn_apply(const float* __restrict__ x, const float* __restrict__ mr,
                                                const float* __restrict__ gamma, const float* __restrict__ beta,
                                                unsigned short* __restrict__ normed) {
  int bid = blockIdx.x;              // b * 4(ctile) * 64(ntile)
  int nt = bid & 63;
  int ct = (bid >> 6) & 3;
  int b = bid >> 8;
  int c0 = ct * 64, n0 = nt * 64;
  __shared__ unsigned short T[64][80];   // [n][c], padded
  int t = threadIdx.x;
#pragma unroll
  for (int it = 0; it < 4; ++it) {
    int idx = it * 256 + t;
    int cl = idx >> 4;
    int n4 = (idx & 15) * 4;
    int c = c0 + cl;
    int bg = b * 32 + (c >> 3);
    float mean = mr[bg], rstd = mr[128 + bg];
    float sc = rstd * gamma[c];
    float sh = beta[c] - mean * sc;
    float4 v = *(const float4*)(x + ((size_t)(b * CC + c)) * NN + n0 + n4);
    T[n4 + 0][cl] = f2bf(v.x * sc + sh);
    T[n4 + 1][cl] = f2bf(v.y * sc + sh);
    T[n4 + 2][cl] = f2bf(v.z * sc + sh);
    T[n4 + 3][cl] = f2bf(v.w * sc + sh);
  }
  __syncthreads();
#pragma unroll
  for (int it = 0; it < 2; ++it) {
    int idx = it * 256 + t;
    int nl = idx >> 3, ck = idx & 7;
    uint4 val;
    unsigned short* pv = (unsigned short*)&val;
#pragma unroll
    for (int j = 0; j < 8; ++j) pv[j] = T[nl][ck * 8 + j];
    *(uint4*)(normed + ((size_t)b * NN + n0 + nl) * CC + c0 + ck * 8) = val;
  }
}

// ---------------- B^T GEMM: C[M][Nc] = A[M][256] * B[Nc][256]^T  (128x128 tiles) ----------------
template <int RESID>
__global__ __launch_bounds__(256) void gemm_bt(const unsigned short* __restrict__ A,
                                               const unsigned short* __restrict__ Bm,
                                               void* __restrict__ Cout, const float* __restrict__ resid,
                                               int mtiles, int ldc,
                                               long sA, long sB, long sC, long sR) {
  int mt = blockIdx.x % mtiles;
  int nt = blockIdx.x / mtiles;
  int b = blockIdx.y;
  int m0 = mt * 128, n0 = nt * 128;
  __shared__ unsigned short As[128][72];
  __shared__ unsigned short Bs[128][72];
  int t = threadIdx.x;
  int w = t >> 6, lane = t & 63;
  int l16 = lane & 15, quad = lane >> 4;
  int wr = w >> 1, wc = w & 1;
  const unsigned short* Ab = A + (size_t)b * sA + (size_t)m0 * 256;
  const unsigned short* Bb = Bm + (size_t)b * sB + (size_t)n0 * 256;
  floatx4 acc[4][4];
#pragma unroll
  for (int m = 0; m < 4; ++m)
#pragma unroll
    for (int n = 0; n < 4; ++n)
#pragma unroll
      for (int r = 0; r < 4; ++r) acc[m][n][r] = 0.f;

  for (int kb = 0; kb < 4; ++kb) {
    __syncthreads();
#pragma unroll
    for (int i = 0; i < 4; ++i) {
      int idx = i * 256 + t;
      int r = idx >> 3, ck = idx & 7;
      *(uint4*)&As[r][ck * 8] = *(const uint4*)(Ab + (size_t)r * 256 + kb * 64 + ck * 8);
      *(uint4*)&Bs[r][ck * 8] = *(const uint4*)(Bb + (size_t)r * 256 + kb * 64 + ck * 8);
    }
    __syncthreads();
#pragma unroll
    for (int kk = 0; kk < 2; ++kk) {
      bf16x8 af[4], bfr[4];
#pragma unroll
      for (int m = 0; m < 4; ++m) af[m] = *(const bf16x8*)&As[wr * 64 + m * 16 + l16][kk * 32 + quad * 8];
#pragma unroll
      for (int n = 0; n < 4; ++n) bfr[n] = *(const bf16x8*)&Bs[wc * 64 + n * 16 + l16][kk * 32 + quad * 8];
#pragma unroll
      for (int m = 0; m < 4; ++m)
#pragma unroll
        for (int n = 0; n < 4; ++n)
          acc[m][n] = __builtin_amdgcn_mfma_f32_16x16x32_bf16(af[m], bfr[n], acc[m][n], 0, 0, 0);
    }
  }
  size_t cb = (size_t)b * sC;
  size_t rb = (size_t)b * sR;
#pragma unroll
  for (int m = 0; m < 4; ++m)
#pragma unroll
    for (int n = 0; n < 4; ++n)
#pragma unroll
      for (int r = 0; r < 4; ++r) {
        int row = m0 + wr * 64 + m * 16 + quad * 4 + r;
        int col = n0 + wc * 64 + n * 16 + l16;
        size_t idx = (size_t)row * ldc + col;
        if (RESID)
          ((float*)Cout)[cb + idx] = acc[m][n][r] + resid[rb + idx];
        else
          ((unsigned short*)Cout)[cb + idx] = f2bf(acc[m][n][r]);
      }
}

// ---------------- fused attention v9: named double buffers (K0/K1/V0/V1 distinct LDS objects)
// so AMDGPU alias analysis can prove the prefetch DMA (into buf B) doesn't alias the compute
// phase's ds_reads (from buf A) -> no vmcnt(0) before ds_read -> DMA truly overlaps compute.
// Everything else identical to v8: grid 256, 512 thr, waves = (iq 0..3 x jh 0..1), zero-dup
// mapping, 256 MFMA + 256 b128 reads per CU-iter, S^T trick, exp2-domain no-max softmax.
__global__ __launch_bounds__(512, 2) void attn(const unsigned short* __restrict__ qk,   // [B][N][512] (q|k)
                                               const unsigned short* __restrict__ vbuf, // [B][C][N]
                                               unsigned short* __restrict__ opart0,     // [B][N][C] bf16 (kh=0)
                                               unsigned short* __restrict__ opart1,     // [B][N][C] bf16 (kh=1)
                                               float* __restrict__ lpart) {             // [B*2][N]
  __shared__ __attribute__((aligned(16))) unsigned short K0[16384];  // 32 KB each
  __shared__ __attribute__((aligned(16))) unsigned short K1[16384];
  __shared__ __attribute__((aligned(16))) unsigned short V0[16384];
  __shared__ __attribute__((aligned(16))) unsigned short V1[16384];
  __shared__ float Lred[256];

  int xcd = blockIdx.x & 7, slot = blockIdx.x >> 3;
  int b = xcd >> 1;
  int kh = xcd & 1;
  int i0 = slot * 128;
  int k0 = kh * 32;

  int t = threadIdx.x, w = t >> 6, l = t & 63;
  int l31 = l & 31, hi = l >> 5;
  int jh = w & 1;            // j-half
  int iq = w >> 1;           // i-quarter

  const size_t bqk = (size_t)b * NN * 512;
  const size_t bv = (size_t)b * CC * NN;

  // DMA stage (v6-verified source math): K [64 j][256 c] 16B-chunk XOR swizzle p^(r&31);
  // V [256 c][64 j] chunk swizzle p^(c&7). Destination arrays are compile-time-named.
  auto stage = [&](int tile, unsigned short* __restrict__ Kd, unsigned short* __restrict__ Vd) {
    const unsigned short* kg = qk + bqk + (size_t)tile * 64 * 512 + 256;
#pragma unroll
    for (int it = 0; it < 4; ++it) {
      int pp = w * 4 + it;                    // instr-block 0..31 (2 rows each)
      int r = 2 * pp + (l >> 5);
      int c = (l & 31) ^ (r & 31);
      async16(kg + (size_t)r * 512 + c * 8, (char*)Kd + pp * 1024);
    }
    const unsigned short* vg = vbuf + bv + (size_t)tile * 64;
    int cj = (l & 7) ^ ((l >> 3) & 7);
#pragma unroll
    for (int it = 0; it < 4; ++it) {
      int pp = w * 4 + it;                    // instr-block 0..31 (8 c-rows each)
      int rc = 8 * pp + (l >> 3);
      async16(vg + (size_t)rc * NN + cj * 8, (char*)Vd + pp * 1024);
    }
  };

  stage(k0, K0, V0);

  // Q fragments (B-operand): lane = i = i0 + iq*32 + l31, elems c = ks*16 + hi*8 + 0..7
  bf16x8 qreg[16];
  {
    const unsigned short* qp = qk + bqk + (size_t)(i0 + iq * 32 + l31) * 512 + hi * 8;
#pragma unroll
    for (int ks = 0; ks < 16; ++ks)
      qreg[ks] = *(const bf16x8*)(qp + ks * 16);
  }

  floatx16 oacc[8];
#pragma unroll
  for (int cf = 0; cf < 8; ++cf)
#pragma unroll
    for (int r = 0; r < 16; ++r) oacc[cf][r] = 0.f;
  float lacc = 0.f;

  // one tile's compute phase against named buffers
  auto phase = [&](const unsigned short* __restrict__ Kc, const unsigned short* __restrict__ Vc) {
    // S^T = K . Q^T for own j-half (D[m=j][n=i]; lane = i)
    floatx16 st;
#pragma unroll
    for (int r = 0; r < 16; ++r) st[r] = 0.f;
#pragma unroll
    for (int ks = 0; ks < 16; ++ks) {
      bf16x8 kf = *(const bf16x8*)&Kc[(jh * 32 + l31) * 256 + (((ks << 1) | hi) ^ l31) * 8];
      st = __builtin_amdgcn_mfma_f32_32x32x16_bf16(kf, qreg[ks], st, 0, 0, 0);
    }
    // P = exp2(S^T); pack bf16 pairs along j
    u32 pr[8];
#pragma unroll
    for (int k2 = 0; k2 < 8; ++k2) {
      float p0 = __builtin_amdgcn_exp2f(st[2 * k2]);
      float p1 = __builtin_amdgcn_exp2f(st[2 * k2 + 1]);
      lacc += p0 + p1;
      pr[k2] = __builtin_amdgcn_perm(fbits(p1), fbits(p0), 0x07060302u);
    }
    // rearrange into PV A-fragments (elems j = jh*32 + s*16 + hi*8 + 0..7) via hi-half exchange
    union U { u32 u[4]; bf16x8 v; } a0, a1;
    {
      u32 sA = hi ? pr[0] : pr[2], sB = hi ? pr[1] : pr[3];
      u32 rA = (u32)__shfl_xor((int)sA, 32, 64);
      u32 rB = (u32)__shfl_xor((int)sB, 32, 64);
      a0.u[0] = hi ? rA : pr[0]; a0.u[1] = hi ? rB : pr[1];
      a0.u[2] = hi ? pr[2] : rA; a0.u[3] = hi ? pr[3] : rB;
      sA = hi ? pr[4] : pr[6]; sB = hi ? pr[5] : pr[7];
      rA = (u32)__shfl_xor((int)sA, 32, 64);
      rB = (u32)__shfl_xor((int)sB, 32, 64);
      a1.u[0] = hi ? rA : pr[4]; a1.u[1] = hi ? rB : pr[5];
      a1.u[2] = hi ? pr[6] : rA; a1.u[3] = hi ? pr[7] : rB;
    }
    // O_partial += P . V over own j-half; full 256 c (B-frag: lane = c = cf*32+l31, elems = j)
#pragma unroll
    for (int cf = 0; cf < 8; ++cf) {
      const unsigned short* vrow = Vc + (cf * 32 + l31) * 64;
      bf16x8 v0 = *(const bf16x8*)(vrow + (((jh * 4) | hi) ^ (l31 & 7)) * 8);
      oacc[cf] = __builtin_amdgcn_mfma_f32_32x32x16_bf16(a0.v, v0, oacc[cf], 0, 0, 0);
      bf16x8 v1 = *(const bf16x8*)(vrow + (((jh * 4 + 2) | hi) ^ (l31 & 7)) * 8);
      oacc[cf] = __builtin_amdgcn_mfma_f32_32x32x16_bf16(a1.v, v1, oacc[cf], 0, 0, 0);
    }
  };

  // 2x-unrolled kt loop: compute on one named pair while DMA fills the other
#pragma unroll 1
  for (int kt = 0; kt < 32; kt += 2) {
    __syncthreads();                       // K0/V0 tile (k0+kt) DMA drained
    if (kt + 1 < 32) stage(k0 + kt + 1, K1, V1);
    phase(K0, V0);
    __syncthreads();                       // K1/V1 tile drained
    if (kt + 2 < 32) stage(k0 + kt + 2, K0, V0);
    if (kt + 1 < 32) phase(K1, V1);
  }

  // ---- epilogue: combine jh pairs. Each iq-wave's Of lives in ONE named 32-KB array. ----
  float l2 = lacc + __shfl_xor(lacc, 32, 64);   // per-lane i = iq*32+l31, own j-half complete

  float* Of = iq == 0 ? (float*)K0 : iq == 1 ? (float*)K1 : iq == 2 ? (float*)V0 : (float*)V1;
  __syncthreads();
  if (jh == 1) {
#pragma unroll
    for (int cf = 0; cf < 8; ++cf)
#pragma unroll
      for (int r = 0; r < 16; ++r) {
        int il = (r & 3) + 8 * (r >> 2) + 4 * hi;
        Of[il * 256 + cf * 32 + l31] = oacc[cf][r];
      }
  }
  if (hi == 0) Lred[w * 32 + l31] = l2;
  __syncthreads();
  unsigned short* ops = kh ? opart1 : opart0;
  size_t rowbase = (size_t)b * NN + i0 + iq * 32;
  if (jh == 0) {
#pragma unroll
    for (int cf = 0; cf < 8; ++cf)
#pragma unroll
      for (int r = 0; r < 16; ++r) {
        int il = (r & 3) + 8 * (r >> 2) + 4 * hi;
        float v = oacc[cf][r] + Of[il * 256 + cf * 32 + l31];
        ops[(rowbase + il) * CC + cf * 32 + l31] = f2bf(v);
      }
    if (hi == 0) {
      size_t pbl = (size_t)(b * 2 + kh) * NN + i0;
      lpart[pbl + iq * 32 + l31] = Lred[(iq * 2) * 32 + l31] + Lred[(iq * 2 + 1) * 32 + l31];
    }
  }
}

// ---------------- proj GEMM with fused K-half combine + residual ----------------
// out[b][co][n] = sum_c wp[co][c] * ((op0[b][n][c]+op1[b][n][c]) / (l0[b][n]+l1[b][n])) + x[b][co][n]
__global__ __launch_bounds__(256) void gemm_proj(const unsigned short* __restrict__ wp,
                                                 const unsigned short* __restrict__ op0,
                                                 const unsigned short* __restrict__ op1,
                                                 const float* __restrict__ lp,
                                                 float* __restrict__ out, const float* __restrict__ x) {
  int mt = blockIdx.x & 1;        // 2 m-tiles over co
  int nt = blockIdx.x >> 1;       // 32 n-tiles
  int b = blockIdx.y;
  int m0 = mt * 128, n0 = nt * 128;
  __shared__ unsigned short As[128][72];
  __shared__ unsigned short Bs[128][72];
  __shared__ float Linv[128];
  int t = threadIdx.x;
  int w = t >> 6, lane = t & 63;
  int l16 = lane & 15, quad = lane >> 4;
  int wr = w >> 1, wc = w & 1;
  const unsigned short* Ab = wp + (size_t)m0 * 256;
  const unsigned short* o0 = op0 + ((size_t)b * NN + n0) * 256;
  const unsigned short* o1 = op1 + ((size_t)b * NN + n0) * 256;
  if (t < 128) Linv[t] = 1.f / (lp[b * 8192 + n0 + t] + lp[b * 8192 + 4096 + n0 + t]);
  floatx4 acc[4][4];
#pragma unroll
  for (int m = 0; m < 4; ++m)
#pragma unroll
    for (int n = 0; n < 4; ++n)
#pragma unroll
      for (int r = 0; r < 4; ++r) acc[m][n][r] = 0.f;

  for (int kb = 0; kb < 4; ++kb) {
    __syncthreads();
#pragma unroll
    for (int i = 0; i < 4; ++i) {
      int idx = i * 256 + t;
      int r = idx >> 3, ck = idx & 7;
      *(uint4*)&As[r][ck * 8] = *(const uint4*)(Ab + (size_t)r * 256 + kb * 64 + ck * 8);
      uint4 u0 = *(const uint4*)(o0 + (size_t)r * 256 + kb * 64 + ck * 8);
      uint4 u1 = *(const uint4*)(o1 + (size_t)r * 256 + kb * 64 + ck * 8);
      float li = Linv[r];
      const unsigned short* pa = (const unsigned short*)&u0;
      const unsigned short* pb = (const unsigned short*)&u1;
      union { unsigned short us[8]; uint4 q; } ob;
#pragma unroll
      for (int j = 0; j < 8; ++j)
        ob.us[j] = f2bf((bf2f(pa[j]) + bf2f(pb[j])) * li);
      *(uint4*)&Bs[r][ck * 8] = ob.q;
    }
    __syncthreads();
#pragma unroll
    for (int kk = 0; kk < 2; ++kk) {
      bf16x8 af[4], bfr[4];
#pragma unroll
      for (int m = 0; m < 4; ++m) af[m] = *(const bf16x8*)&As[wr * 64 + m * 16 + l16][kk * 32 + quad * 8];
#pragma unroll
      for (int n = 0; n < 4; ++n) bfr[n] = *(const bf16x8*)&Bs[wc * 64 + n * 16 + l16][kk * 32 + quad * 8];
#pragma unroll
      for (int m = 0; m < 4; ++m)
#pragma unroll
        for (int n = 0; n < 4; ++n)
          acc[m][n] = __builtin_amdgcn_mfma_f32_16x16x32_bf16(af[m], bfr[n], acc[m][n], 0, 0, 0);
    }
  }
  size_t cb = (size_t)b * CC * NN;
#pragma unroll
  for (int m = 0; m < 4; ++m)
#pragma unroll
    for (int n = 0; n < 4; ++n)
#pragma unroll
      for (int r = 0; r < 4; ++r) {
        int row = m0 + wr * 64 + m * 16 + quad * 4 + r;
        int col = n0 + wc * 64 + n * 16 + l16;
        size_t idx = cb + (size_t)row * NN + col;
        out[idx] = acc[m][n][r] + x[idx];
      }
}

extern "C" void kernel_launch(void* const* d_in, const int* in_sizes, int n_in,
                              void* d_out, int out_size, void* d_ws, size_t ws_size,
                              hipStream_t stream) {
  const float* x     = (const float*)d_in[0];
  // d_in[1] = t (unused)
  const float* gamma = (const float*)d_in[2];
  const float* beta  = (const float*)d_in[3];
  const float* wqkv  = (const float*)d_in[4];
  const float* wproj = (const float*)d_in[5];
  float* out = (float*)d_out;

  // Workspace layout (max 42,468,352 B — proven footprint):
  //   [0,1024)            mr (dead after gn_apply)
  //   [1024, 394240)      wq_bf 384 KB (dead after v-GEMM) — lpart (128 KB) overlays @1024
  //   [394240, 525312)    wp_bf 128 KB (live until proj GEMM)
  //   [525312, 8913920)   normed 8 MB (dead after v-GEMM) — opart0 overlays
  //   [8913920, 25691136) qkbuf 16 MB (dead after attn)
  //   [25691136,34079744) vbuf 8 MB
  //   [34079744,42468352) opart1 8 MB
  char* p = (char*)d_ws;
  float* mr               = (float*)(p + 0);
  unsigned short* wq_bf   = (unsigned short*)(p + 1024);
  unsigned short* wp_bf   = (unsigned short*)(p + 394240);
  unsigned short* normed  = (unsigned short*)(p + 525312);
  unsigned short* qkbuf   = (unsigned short*)(p + 8913920);
  unsigned short* vbuf    = (unsigned short*)(p + 25691136);
  unsigned short* opart1  = (unsigned short*)(p + 34079744);
  unsigned short* opart0  = normed;                            // overlay (normed dead after v-GEMM)
  float* lpart            = (float*)(p + 1024);                // overlay (wq_bf dead after v-GEMM)
  unsigned short* obufdummy = nullptr; (void)obufdummy;
  unsigned short* wv_bf   = wq_bf + 512 * 256;

  gn_stats_wconv<<<1152, 256, 0, stream>>>(x, mr, wqkv, wproj, wq_bf, wp_bf);
  gn_apply<<<1024, 256, 0, stream>>>(x, mr, gamma, beta, normed);
  // qk[b][n][o] = normed[b][n][:] . wqkv[o][:]  (o<512)
  gemm_bt<0><<<dim3(128, 4), 256, 0, stream>>>(normed, wq_bf, qkbuf, nullptr,
                                               32, 512, (long)NN * CC, 0L, (long)NN * 512, 0L);
  // v[b][c][n] = wv[c][:] . normed[b][n][:]
  gemm_bt<0><<<dim3(64, 4), 256, 0, stream>>>(wv_bf, normed, vbuf, nullptr,
                                              2, 4096, 0L, (long)NN * CC, (long)CC * NN, 0L);
  attn<<<256, 512, 0, stream>>>(qkbuf, vbuf, opart0, opart1, lpart);
  // out = wproj . combine(op0,op1,l) + x   (combine fused into B-staging)
  gemm_proj<<<dim3(64, 4), 256, 0, stream>>>(wp_bf, opart0, opart1, lpart, out, x);
}

// Round 10
// 195.443 us; speedup vs baseline: 1.1099x; 1.1099x over previous
//
#include <hip/hip_runtime.h>

typedef __bf16 bf16x8 __attribute__((ext_vector_type(8)));
typedef float floatx4 __attribute__((ext_vector_type(4)));
typedef float floatx16 __attribute__((ext_vector_type(16)));
typedef unsigned int u32;

#define BB 4
#define CC 256
#define NN 4096

__device__ __forceinline__ unsigned short f2bf(float f) {
  union { float f; unsigned u; } v; v.f = f;
  unsigned r = v.u + 0x7fffu + ((v.u >> 16) & 1u);
  return (unsigned short)(r >> 16);
}

__device__ __forceinline__ float bf2f(unsigned short s) {
  union { unsigned u; float f; } v; v.u = ((u32)s) << 16;
  return v.f;
}

__device__ __forceinline__ void async16(const void* g, void* l) {
  __builtin_amdgcn_global_load_lds((const __attribute__((address_space(1))) u32*)g,
                                   (__attribute__((address_space(3))) u32*)l, 16, 0, 0);
}

__device__ __forceinline__ u32 fbits(float f) {
  union { float f; u32 u; } v; v.f = f; return v.u;
}

// ------- GroupNorm stats (blocks 1024..1151) + weight bf16 convert (blocks 0..1023) ----------
__global__ __launch_bounds__(256) void gn_stats_wconv(const float* __restrict__ x, float* __restrict__ mr,
                                                      const float* __restrict__ wqkv, const float* __restrict__ wproj,
                                                      unsigned short* __restrict__ wq_bf, unsigned short* __restrict__ wp_bf) {
  if (blockIdx.x < 1024) {
    int i = blockIdx.x * 256 + threadIdx.x;
    if (i < 196608) {
      float v = wqkv[i];
      if (i < 65536) v *= 0.090168440055560213f;  // log2(e)/16
      wq_bf[i] = f2bf(v);
    } else {
      int j = i - 196608;
      wp_bf[j] = f2bf(wproj[j]);
    }
    return;
  }
  int bg = blockIdx.x - 1024;
  const float* p = x + (size_t)bg * 32768;
  int t = threadIdx.x;
  float s = 0.f, q = 0.f;
#pragma unroll
  for (int it = 0; it < 32; ++it) {
    float4 v = *(const float4*)(p + it * 1024 + t * 4);
    s += v.x + v.y + v.z + v.w;
    q += v.x * v.x + v.y * v.y + v.z * v.z + v.w * v.w;
  }
#pragma unroll
  for (int off = 1; off < 64; off <<= 1) {
    s += __shfl_xor(s, off, 64);
    q += __shfl_xor(q, off, 64);
  }
  __shared__ float red[8];
  int w = t >> 6;
  if ((t & 63) == 0) { red[w] = s; red[4 + w] = q; }
  __syncthreads();
  if (t == 0) {
    float S = red[0] + red[1] + red[2] + red[3];
    float Q = red[4] + red[5] + red[6] + red[7];
    float mean = S * (1.f / 32768.f);
    float var = Q * (1.f / 32768.f) - mean * mean;
    mr[bg] = mean;
    mr[128 + bg] = rsqrtf(var + 1e-5f);
  }
}

// ---------------- normalize + transpose to normed[b][n][c] bf16 ----------------
__global__ __launch_bounds__(256) void gn_apply(const float* __restrict__ x, const float* __restrict__ mr,
                                                const float* __restrict__ gamma, const float* __restrict__ beta,
                                                unsigned short* __restrict__ normed) {
  int bid = blockIdx.x;              // b * 4(ctile) * 64(ntile)
  int nt = bid & 63;
  int ct = (bid >> 6) & 3;
  int b = bid >> 8;
  int c0 = ct * 64, n0 = nt * 64;
  __shared__ unsigned short T[64][80];   // [n][c], padded
  int t = threadIdx.x;
#pragma unroll
  for (int it = 0; it < 4; ++it) {
    int idx = it * 256 + t;
    int cl = idx >> 4;
    int n4 = (idx & 15) * 4;
    int c = c0 + cl;
    int bg = b * 32 + (c >> 3);
    float mean = mr[bg], rstd = mr[128 + bg];
    float sc = rstd * gamma[c];
    float sh = beta[c] - mean * sc;
    float4 v = *(const float4*)(x + ((size_t)(b * CC + c)) * NN + n0 + n4);
    T[n4 + 0][cl] = f2bf(v.x * sc + sh);
    T[n4 + 1][cl] = f2bf(v.y * sc + sh);
    T[n4 + 2][cl] = f2bf(v.z * sc + sh);
    T[n4 + 3][cl] = f2bf(v.w * sc + sh);
  }
  __syncthreads();
#pragma unroll
  for (int it = 0; it < 2; ++it) {
    int idx = it * 256 + t;
    int nl = idx >> 3, ck = idx & 7;
    uint4 val;
    unsigned short* pv = (unsigned short*)&val;
#pragma unroll
    for (int j = 0; j < 8; ++j) pv[j] = T[nl][ck * 8 + j];
    *(uint4*)(normed + ((size_t)b * NN + n0 + nl) * CC + c0 + ck * 8) = val;
  }
}

// ------- B^T GEMM v2: DMA double-buffered staging, 128x128 tiles, XOR-swizzled LDS ----------
// C[M][Nc] = A[M][256] * B[Nc][256]^T. LDS: A0|A1|B0|B1 16 KB each (unpadded [128][64],
// 16B-chunk pos = chunk ^ (row&7) — DMA-compatible, conflict-free fragment reads).
template <int RESID>
__global__ __launch_bounds__(256, 2) void gemm_bt2(const unsigned short* __restrict__ A,
                                                   const unsigned short* __restrict__ Bm,
                                                   void* __restrict__ Cout, const float* __restrict__ resid,
                                                   int mtiles, int ldc,
                                                   long sA, long sB, long sC, long sR) {
  __shared__ __attribute__((aligned(16))) char smem[65536];
  int mt = blockIdx.x % mtiles;
  int nt = blockIdx.x / mtiles;
  int b = blockIdx.y;
  int m0 = mt * 128, n0 = nt * 128;
  int t = threadIdx.x, w = t >> 6, l = t & 63;
  int l16 = l & 15, quad = l >> 4;
  int wr = w >> 1, wc = w & 1;
  const unsigned short* Ab = A + (size_t)b * sA + (size_t)m0 * 256;
  const unsigned short* Bb = Bm + (size_t)b * sB + (size_t)n0 * 256;

  // DMA one 128x64 A-tile + B-tile for K-block kb into buffer `buf`.
  // Per instr: 8 rows; lane l -> row 8*pp + (l>>3), fetches global chunk (l&7)^(l>>3)
  // into pos l&7  =>  stored pos = data_chunk ^ (row&7).
  auto stage = [&](int kb, int buf) {
    int rsub = l >> 3;
    int cj = (l & 7) ^ rsub;
    char* ab = smem + buf * 16384;
    char* bb = smem + 32768 + buf * 16384;
#pragma unroll
    for (int it = 0; it < 4; ++it) {
      int pp = w * 4 + it;              // 16 instr-blocks of 8 rows
      size_t go = (size_t)(8 * pp + rsub) * 256 + kb * 64 + cj * 8;
      async16(Ab + go, ab + pp * 1024);
      async16(Bb + go, bb + pp * 1024);
    }
  };

  floatx4 acc[4][4];
#pragma unroll
  for (int m = 0; m < 4; ++m)
#pragma unroll
    for (int n = 0; n < 4; ++n)
#pragma unroll
      for (int r = 0; r < 4; ++r) acc[m][n][r] = 0.f;

  stage(0, 0);

#pragma unroll 1
  for (int kb = 0; kb < 4; ++kb) {
    int cur = kb & 1;
    __syncthreads();                    // tile kb DMA drained; prev-buf readers done
    if (kb < 3) stage(kb + 1, cur ^ 1); // in flight during compute
    const unsigned short* As = (const unsigned short*)(smem + cur * 16384);
    const unsigned short* Bs = (const unsigned short*)(smem + 32768 + cur * 16384);
#pragma unroll
    for (int kk = 0; kk < 2; ++kk) {
      bf16x8 af[4], bfr[4];
      int sw = ((kk * 4 + quad) ^ (l16 & 7)) * 8;
#pragma unroll
      for (int m = 0; m < 4; ++m)
        af[m] = *(const bf16x8*)&As[(wr * 64 + m * 16 + l16) * 64 + sw];
#pragma unroll
      for (int n = 0; n < 4; ++n)
        bfr[n] = *(const bf16x8*)&Bs[(wc * 64 + n * 16 + l16) * 64 + sw];
#pragma unroll
      for (int m = 0; m < 4; ++m)
#pragma unroll
        for (int n = 0; n < 4; ++n)
          acc[m][n] = __builtin_amdgcn_mfma_f32_16x16x32_bf16(af[m], bfr[n], acc[m][n], 0, 0, 0);
    }
  }

  size_t cb = (size_t)b * sC;
  size_t rb = (size_t)b * sR;
#pragma unroll
  for (int m = 0; m < 4; ++m)
#pragma unroll
    for (int n = 0; n < 4; ++n)
#pragma unroll
      for (int r = 0; r < 4; ++r) {
        int row = m0 + wr * 64 + m * 16 + quad * 4 + r;
        int col = n0 + wc * 64 + n * 16 + l16;
        size_t idx = (size_t)row * ldc + col;
        if (RESID)
          ((float*)Cout)[cb + idx] = acc[m][n][r] + resid[rb + idx];
        else
          ((unsigned short*)Cout)[cb + idx] = f2bf(acc[m][n][r]);
      }
}

// ---------------- fused attention (v8, proven 89.4 us): waves = (iq x jh), zero duplication --
__global__ __launch_bounds__(512, 2) void attn(const unsigned short* __restrict__ qk,   // [B][N][512] (q|k)
                                               const unsigned short* __restrict__ vbuf, // [B][C][N]
                                               unsigned short* __restrict__ opart0,     // [B][N][C] bf16 (kh=0)
                                               unsigned short* __restrict__ opart1,     // [B][N][C] bf16 (kh=1)
                                               float* __restrict__ lpart) {             // [B*2][N]
  __shared__ __attribute__((aligned(16))) char smem[131072]; // K0|K1|V0|V1, 32 KB each

  int xcd = blockIdx.x & 7, slot = blockIdx.x >> 3;
  int b = xcd >> 1;
  int kh = xcd & 1;
  int i0 = slot * 128;
  int k0 = kh * 32;

  int t = threadIdx.x, w = t >> 6, l = t & 63;
  int l31 = l & 31, hi = l >> 5;
  int jh = w & 1;            // j-half
  int iq = w >> 1;           // i-quarter

  const size_t bqk = (size_t)b * NN * 512;
  const size_t bv = (size_t)b * CC * NN;

  auto stage = [&](int tile, int buf) {
    const unsigned short* kg = qk + bqk + (size_t)tile * 64 * 512 + 256;
    char* kb = smem + buf * 32768;
#pragma unroll
    for (int it = 0; it < 4; ++it) {
      int pp = w * 4 + it;                    // instr-block 0..31 (2 rows each)
      int r = 2 * pp + (l >> 5);
      int c = (l & 31) ^ (r & 31);
      async16(kg + (size_t)r * 512 + c * 8, kb + pp * 1024);
    }
    const unsigned short* vg = vbuf + bv + (size_t)tile * 64;
    char* vb = smem + 65536 + buf * 32768;
    int cj = (l & 7) ^ ((l >> 3) & 7);
#pragma unroll
    for (int it = 0; it < 4; ++it) {
      int pp = w * 4 + it;                    // instr-block 0..31 (8 c-rows each)
      int rc = 8 * pp + (l >> 3);
      async16(vg + (size_t)rc * NN + cj * 8, vb + pp * 1024);
    }
  };

  stage(k0, 0);

  // Q fragments (B-operand): lane = i = i0 + iq*32 + l31, elems c = ks*16 + hi*8 + 0..7
  bf16x8 qreg[16];
  {
    const unsigned short* qp = qk + bqk + (size_t)(i0 + iq * 32 + l31) * 512 + hi * 8;
#pragma unroll
    for (int ks = 0; ks < 16; ++ks)
      qreg[ks] = *(const bf16x8*)(qp + ks * 16);
  }

  floatx16 oacc[8];
#pragma unroll
  for (int cf = 0; cf < 8; ++cf)
#pragma unroll
    for (int r = 0; r < 16; ++r) oacc[cf][r] = 0.f;
  float lacc = 0.f;

  for (int kt = 0; kt < 32; ++kt) {
    int cur = kt & 1;
    __syncthreads();                      // tile kt DMA drained; all waves past prev buf reads
    if (kt < 31) stage(k0 + kt + 1, cur ^ 1);   // in flight during compute below

    const unsigned short* Kc = (const unsigned short*)(smem + cur * 32768);
    const unsigned short* Vc = (const unsigned short*)(smem + 65536 + cur * 32768);

    // S^T = K . Q^T for own j-half (D[m=j][n=i]; lane = i)
    floatx16 st;
#pragma unroll
    for (int r = 0; r < 16; ++r) st[r] = 0.f;
#pragma unroll
    for (int ks = 0; ks < 16; ++ks) {
      bf16x8 kf = *(const bf16x8*)&Kc[(jh * 32 + l31) * 256 + (((ks << 1) | hi) ^ l31) * 8];
      st = __builtin_amdgcn_mfma_f32_32x32x16_bf16(kf, qreg[ks], st, 0, 0, 0);
    }

    // P = exp2(S^T); pack bf16 pairs along j
    u32 pr[8];
#pragma unroll
    for (int k2 = 0; k2 < 8; ++k2) {
      float p0 = __builtin_amdgcn_exp2f(st[2 * k2]);
      float p1 = __builtin_amdgcn_exp2f(st[2 * k2 + 1]);
      lacc += p0 + p1;
      pr[k2] = __builtin_amdgcn_perm(fbits(p1), fbits(p0), 0x07060302u);
    }

    // rearrange into PV A-fragments (elems j = jh*32 + s*16 + hi*8 + 0..7) via hi-half exchange
    union U { u32 u[4]; bf16x8 v; } a0, a1;
    {
      u32 sA = hi ? pr[0] : pr[2], sB = hi ? pr[1] : pr[3];
      u32 rA = (u32)__shfl_xor((int)sA, 32, 64);
      u32 rB = (u32)__shfl_xor((int)sB, 32, 64);
      a0.u[0] = hi ? rA : pr[0]; a0.u[1] = hi ? rB : pr[1];
      a0.u[2] = hi ? pr[2] : rA; a0.u[3] = hi ? pr[3] : rB;
      sA = hi ? pr[4] : pr[6]; sB = hi ? pr[5] : pr[7];
      rA = (u32)__shfl_xor((int)sA, 32, 64);
      rB = (u32)__shfl_xor((int)sB, 32, 64);
      a1.u[0] = hi ? rA : pr[4]; a1.u[1] = hi ? rB : pr[5];
      a1.u[2] = hi ? pr[6] : rA; a1.u[3] = hi ? pr[7] : rB;
    }

    // O_partial += P . V over own j-half; full 256 c (B-frag: lane = c = cf*32+l31, elems = j)
#pragma unroll
    for (int cf = 0; cf < 8; ++cf) {
      const unsigned short* vrow = Vc + (cf * 32 + l31) * 64;
      bf16x8 v0 = *(const bf16x8*)(vrow + (((jh * 4) | hi) ^ (l31 & 7)) * 8);
      oacc[cf] = __builtin_amdgcn_mfma_f32_32x32x16_bf16(a0.v, v0, oacc[cf], 0, 0, 0);
      bf16x8 v1 = *(const bf16x8*)(vrow + (((jh * 4 + 2) | hi) ^ (l31 & 7)) * 8);
      oacc[cf] = __builtin_amdgcn_mfma_f32_32x32x16_bf16(a1.v, v1, oacc[cf], 0, 0, 0);
    }
  }

  // ---- epilogue: combine jh pairs. Phase A: O via LDS overlay (dead K/V buffers).
  float l2 = lacc + __shfl_xor(lacc, 32, 64);   // per-lane i = iq*32+l31, own j-half complete

  float* Of = (float*)smem + iq * 8192;         // [32 i][256 c] fp32 per iq (32 KB each)
  __syncthreads();
  if (jh == 1) {
#pragma unroll
    for (int cf = 0; cf < 8; ++cf)
#pragma unroll
      for (int r = 0; r < 16; ++r) {
        int il = (r & 3) + 8 * (r >> 2) + 4 * hi;
        Of[il * 256 + cf * 32 + l31] = oacc[cf][r];
      }
  }
  __syncthreads();
  unsigned short* ops = kh ? opart1 : opart0;
  size_t rowbase = (size_t)b * NN + i0 + iq * 32;
  if (jh == 0) {
#pragma unroll
    for (int cf = 0; cf < 8; ++cf)
#pragma unroll
      for (int r = 0; r < 16; ++r) {
        int il = (r & 3) + 8 * (r >> 2) + 4 * hi;
        float v = oacc[cf][r] + Of[il * 256 + cf * 32 + l31];
        ops[(rowbase + il) * CC + cf * 32 + l31] = f2bf(v);
      }
  }
  __syncthreads();
  // Phase B: l via small LDS pass
  float* Lred = (float*)smem;                   // [8 waves][32]
  if (hi == 0) Lred[w * 32 + l31] = l2;
  __syncthreads();
  if (jh == 0 && hi == 0) {
    size_t pbl = (size_t)(b * 2 + kh) * NN + i0;
    lpart[pbl + iq * 32 + l31] = Lred[(iq * 2) * 32 + l31] + Lred[(iq * 2 + 1) * 32 + l31];
  }
}

// ---------------- proj GEMM with fused K-half combine + residual ----------------
// out[b][co][n] = sum_c wp[co][c] * ((op0[b][n][c]+op1[b][n][c]) / (l0[b][n]+l1[b][n])) + x[b][co][n]
__global__ __launch_bounds__(256) void gemm_proj(const unsigned short* __restrict__ wp,
                                                 const unsigned short* __restrict__ op0,
                                                 const unsigned short* __restrict__ op1,
                                                 const float* __restrict__ lp,
                                                 float* __restrict__ out, const float* __restrict__ x) {
  int mt = blockIdx.x & 1;        // 2 m-tiles over co
  int nt = blockIdx.x >> 1;       // 32 n-tiles
  int b = blockIdx.y;
  int m0 = mt * 128, n0 = nt * 128;
  __shared__ unsigned short As[128][72];
  __shared__ unsigned short Bs[128][72];
  __shared__ float Linv[128];
  int t = threadIdx.x;
  int w = t >> 6, lane = t & 63;
  int l16 = lane & 15, quad = lane >> 4;
  int wr = w >> 1, wc = w & 1;
  const unsigned short* Ab = wp + (size_t)m0 * 256;
  const unsigned short* o0 = op0 + ((size_t)b * NN + n0) * 256;
  const unsigned short* o1 = op1 + ((size_t)b * NN + n0) * 256;
  if (t < 128) Linv[t] = 1.f / (lp[b * 8192 + n0 + t] + lp[b * 8192 + 4096 + n0 + t]);
  floatx4 acc[4][4];
#pragma unroll
  for (int m = 0; m < 4; ++m)
#pragma unroll
    for (int n = 0; n < 4; ++n)
#pragma unroll
      for (int r = 0; r < 4; ++r) acc[m][n][r] = 0.f;

  for (int kb = 0; kb < 4; ++kb) {
    __syncthreads();
#pragma unroll
    for (int i = 0; i < 4; ++i) {
      int idx = i * 256 + t;
      int r = idx >> 3, ck = idx & 7;
      *(uint4*)&As[r][ck * 8] = *(const uint4*)(Ab + (size_t)r * 256 + kb * 64 + ck * 8);
      uint4 u0 = *(const uint4*)(o0 + (size_t)r * 256 + kb * 64 + ck * 8);
      uint4 u1 = *(const uint4*)(o1 + (size_t)r * 256 + kb * 64 + ck * 8);
      float li = Linv[r];
      const unsigned short* pa = (const unsigned short*)&u0;
      const unsigned short* pb = (const unsigned short*)&u1;
      union { unsigned short us[8]; uint4 q; } ob;
#pragma unroll
      for (int j = 0; j < 8; ++j)
        ob.us[j] = f2bf((bf2f(pa[j]) + bf2f(pb[j])) * li);
      *(uint4*)&Bs[r][ck * 8] = ob.q;
    }
    __syncthreads();
#pragma unroll
    for (int kk = 0; kk < 2; ++kk) {
      bf16x8 af[4], bfr[4];
#pragma unroll
      for (int m = 0; m < 4; ++m) af[m] = *(const bf16x8*)&As[wr * 64 + m * 16 + l16][kk * 32 + quad * 8];
#pragma unroll
      for (int n = 0; n < 4; ++n) bfr[n] = *(const bf16x8*)&Bs[wc * 64 + n * 16 + l16][kk * 32 + quad * 8];
#pragma unroll
      for (int m = 0; m < 4; ++m)
#pragma unroll
        for (int n = 0; n < 4; ++n)
          acc[m][n] = __builtin_amdgcn_mfma_f32_16x16x32_bf16(af[m], bfr[n], acc[m][n], 0, 0, 0);
    }
  }
  size_t cb = (size_t)b * CC * NN;
#pragma unroll
  for (int m = 0; m < 4; ++m)
#pragma unroll
    for (int n = 0; n < 4; ++n)
#pragma unroll
      for (int r = 0; r < 4; ++r) {
        int row = m0 + wr * 64 + m * 16 + quad * 4 + r;
        int col = n0 + wc * 64 + n * 16 + l16;
        size_t idx = cb + (size_t)row * NN + col;
        out[idx] = acc[m][n][r] + x[idx];
      }
}

extern "C" void kernel_launch(void* const* d_in, const int* in_sizes, int n_in,
                              void* d_out, int out_size, void* d_ws, size_t ws_size,
                              hipStream_t stream) {
  const float* x     = (const float*)d_in[0];
  // d_in[1] = t (unused)
  const float* gamma = (const float*)d_in[2];
  const float* beta  = (const float*)d_in[3];
  const float* wqkv  = (const float*)d_in[4];
  const float* wproj = (const float*)d_in[5];
  float* out = (float*)d_out;

  // Workspace layout (max 42,468,352 B — proven footprint):
  //   [0,1024)            mr (dead after gn_apply)
  //   [1024, 394240)      wq_bf 384 KB (dead after v-GEMM) — lpart (128 KB) overlays @1024
  //   [394240, 525312)    wp_bf 128 KB (live until proj GEMM)
  //   [525312, 8913920)   normed 8 MB (dead after v-GEMM) — opart0 overlays
  //   [8913920, 25691136) qkbuf 16 MB (dead after attn)
  //   [25691136,34079744) vbuf 8 MB
  //   [34079744,42468352) opart1 8 MB
  char* p = (char*)d_ws;
  float* mr               = (float*)(p + 0);
  unsigned short* wq_bf   = (unsigned short*)(p + 1024);
  unsigned short* wp_bf   = (unsigned short*)(p + 394240);
  unsigned short* normed  = (unsigned short*)(p + 525312);
  unsigned short* qkbuf   = (unsigned short*)(p + 8913920);
  unsigned short* vbuf    = (unsigned short*)(p + 25691136);
  unsigned short* opart1  = (unsigned short*)(p + 34079744);
  unsigned short* opart0  = normed;                            // overlay (normed dead after v-GEMM)
  float* lpart            = (float*)(p + 1024);                // overlay (wq_bf dead after v-GEMM)
  unsigned short* wv_bf   = wq_bf + 512 * 256;

  gn_stats_wconv<<<1152, 256, 0, stream>>>(x, mr, wqkv, wproj, wq_bf, wp_bf);
  gn_apply<<<1024, 256, 0, stream>>>(x, mr, gamma, beta, normed);
  // qk[b][n][o] = normed[b][n][:] . wqkv[o][:]  (o<512)
  gemm_bt2<0><<<dim3(128, 4), 256, 0, stream>>>(normed, wq_bf, qkbuf, nullptr,
                                                32, 512, (long)NN * CC, 0L, (long)NN * 512, 0L);
  // v[b][c][n] = wv[c][:] . normed[b][n][:]
  gemm_bt2<0><<<dim3(64, 4), 256, 0, stream>>>(wv_bf, normed, vbuf, nullptr,
                                               2, 4096, 0L, (long)NN * CC, (long)CC * NN, 0L);
  attn<<<256, 512, 0, stream>>>(qkbuf, vbuf, opart0, opart1, lpart);
  // out = wproj . combine(op0,op1,l) + x   (combine fused into B-staging)
  gemm_proj<<<dim3(64, 4), 256, 0, stream>>>(wp_bf, opart0, opart1, lpart, out, x);
}

// Round 11
// 185.652 us; speedup vs baseline: 1.1685x; 1.0527x over previous
//
#include <hip/hip_runtime.h>

typedef __bf16 bf16x8 __attribute__((ext_vector_type(8)));
typedef float floatx4 __attribute__((ext_vector_type(4)));
typedef float floatx16 __attribute__((ext_vector_type(16)));
typedef unsigned int u32;

#define BB 4
#define CC 256
#define NN 4096

__device__ __forceinline__ unsigned short f2bf(float f) {
  union { float f; unsigned u; } v; v.f = f;
  unsigned r = v.u + 0x7fffu + ((v.u >> 16) & 1u);
  return (unsigned short)(r >> 16);
}

__device__ __forceinline__ float bf2f(unsigned short s) {
  union { unsigned u; float f; } v; v.u = ((u32)s) << 16;
  return v.f;
}

__device__ __forceinline__ void async16(const void* g, void* l) {
  __builtin_amdgcn_global_load_lds((const __attribute__((address_space(1))) u32*)g,
                                   (__attribute__((address_space(3))) u32*)l, 16, 0, 0);
}

__device__ __forceinline__ u32 fbits(float f) {
  union { float f; u32 u; } v; v.f = f; return v.u;
}

// ------- GroupNorm stats (blocks 1024..1151) + weight bf16 convert (blocks 0..1023) ----------
__global__ __launch_bounds__(256) void gn_stats_wconv(const float* __restrict__ x, float* __restrict__ mr,
                                                      const float* __restrict__ wqkv, const float* __restrict__ wproj,
                                                      unsigned short* __restrict__ wq_bf, unsigned short* __restrict__ wp_bf) {
  if (blockIdx.x < 1024) {
    int i = blockIdx.x * 256 + threadIdx.x;
    if (i < 196608) {
      float v = wqkv[i];
      if (i < 65536) v *= 0.090168440055560213f;  // log2(e)/16
      wq_bf[i] = f2bf(v);
    } else {
      int j = i - 196608;
      wp_bf[j] = f2bf(wproj[j]);
    }
    return;
  }
  int bg = blockIdx.x - 1024;
  const float* p = x + (size_t)bg * 32768;
  int t = threadIdx.x;
  float s = 0.f, q = 0.f;
#pragma unroll
  for (int it = 0; it < 32; ++it) {
    float4 v = *(const float4*)(p + it * 1024 + t * 4);
    s += v.x + v.y + v.z + v.w;
    q += v.x * v.x + v.y * v.y + v.z * v.z + v.w * v.w;
  }
#pragma unroll
  for (int off = 1; off < 64; off <<= 1) {
    s += __shfl_xor(s, off, 64);
    q += __shfl_xor(q, off, 64);
  }
  __shared__ float red[8];
  int w = t >> 6;
  if ((t & 63) == 0) { red[w] = s; red[4 + w] = q; }
  __syncthreads();
  if (t == 0) {
    float S = red[0] + red[1] + red[2] + red[3];
    float Q = red[4] + red[5] + red[6] + red[7];
    float mean = S * (1.f / 32768.f);
    float var = Q * (1.f / 32768.f) - mean * mean;
    mr[bg] = mean;
    mr[128 + bg] = rsqrtf(var + 1e-5f);
  }
}

// ---------------- normalize + transpose to normed[b][n][c] bf16 ----------------
__global__ __launch_bounds__(256) void gn_apply(const float* __restrict__ x, const float* __restrict__ mr,
                                                const float* __restrict__ gamma, const float* __restrict__ beta,
                                                unsigned short* __restrict__ normed) {
  int bid = blockIdx.x;              // b * 4(ctile) * 64(ntile)
  int nt = bid & 63;
  int ct = (bid >> 6) & 3;
  int b = bid >> 8;
  int c0 = ct * 64, n0 = nt * 64;
  __shared__ unsigned short T[64][80];   // [n][c], padded
  int t = threadIdx.x;
#pragma unroll
  for (int it = 0; it < 4; ++it) {
    int idx = it * 256 + t;
    int cl = idx >> 4;
    int n4 = (idx & 15) * 4;
    int c = c0 + cl;
    int bg = b * 32 + (c >> 3);
    float mean = mr[bg], rstd = mr[128 + bg];
    float sc = rstd * gamma[c];
    float sh = beta[c] - mean * sc;
    float4 v = *(const float4*)(x + ((size_t)(b * CC + c)) * NN + n0 + n4);
    T[n4 + 0][cl] = f2bf(v.x * sc + sh);
    T[n4 + 1][cl] = f2bf(v.y * sc + sh);
    T[n4 + 2][cl] = f2bf(v.z * sc + sh);
    T[n4 + 3][cl] = f2bf(v.w * sc + sh);
  }
  __syncthreads();
#pragma unroll
  for (int it = 0; it < 2; ++it) {
    int idx = it * 256 + t;
    int nl = idx >> 3, ck = idx & 7;
    uint4 val;
    unsigned short* pv = (unsigned short*)&val;
#pragma unroll
    for (int j = 0; j < 8; ++j) pv[j] = T[nl][ck * 8 + j];
    *(uint4*)(normed + ((size_t)b * NN + n0 + nl) * CC + c0 + ck * 8) = val;
  }
}

// ------- merged qkv + v GEMM (one dispatch): DMA double-buffered, 128x128 tiles -------------
// blocks x<128: qk[b][n][o<512] = normed[b][n][:] . wq[o][:]   (mt = x%32, nt = x/32)
// blocks x>=128: v[b][c][n]     = wv[c][:] . normed[b][n][:]   (mt = (x-128)&1, nt = (x-128)>>1)
__global__ __launch_bounds__(256, 2) void gemm_qkv_v(const unsigned short* __restrict__ normed,
                                                     const unsigned short* __restrict__ wq_bf,
                                                     const unsigned short* __restrict__ wv_bf,
                                                     unsigned short* __restrict__ qkbuf,
                                                     unsigned short* __restrict__ vbuf) {
  __shared__ __attribute__((aligned(16))) char smem[65536];
  int b = blockIdx.y;
  const unsigned short *Ab, *Bb;
  unsigned short* Cb;
  int ldc, m0, n0;
  if (blockIdx.x < 128) {
    int mt = blockIdx.x % 32, nt = blockIdx.x / 32;
    m0 = mt * 128; n0 = nt * 128;
    Ab = normed + (size_t)b * NN * CC + (size_t)m0 * 256;
    Bb = wq_bf + (size_t)n0 * 256;
    Cb = qkbuf + (size_t)b * NN * 512;
    ldc = 512;
  } else {
    int xx = blockIdx.x - 128;
    int mt = xx & 1, nt = xx >> 1;
    m0 = mt * 128; n0 = nt * 128;
    Ab = wv_bf + (size_t)m0 * 256;
    Bb = normed + (size_t)b * NN * CC + (size_t)n0 * 256;
    Cb = vbuf + (size_t)b * CC * NN;
    ldc = NN;
  }
  int t = threadIdx.x, w = t >> 6, l = t & 63;
  int l16 = l & 15, quad = l >> 4;
  int wr = w >> 1, wc = w & 1;

  // DMA one 128x64 A-tile + B-tile for K-block kb into buffer `buf` (pos = chunk ^ (row&7)).
  auto stage = [&](int kb, int buf) {
    int rsub = l >> 3;
    int cj = (l & 7) ^ rsub;
    char* ab = smem + buf * 16384;
    char* bb = smem + 32768 + buf * 16384;
#pragma unroll
    for (int it = 0; it < 4; ++it) {
      int pp = w * 4 + it;              // 16 instr-blocks of 8 rows
      size_t go = (size_t)(8 * pp + rsub) * 256 + kb * 64 + cj * 8;
      async16(Ab + go, ab + pp * 1024);
      async16(Bb + go, bb + pp * 1024);
    }
  };

  floatx4 acc[4][4];
#pragma unroll
  for (int m = 0; m < 4; ++m)
#pragma unroll
    for (int n = 0; n < 4; ++n)
#pragma unroll
      for (int r = 0; r < 4; ++r) acc[m][n][r] = 0.f;

  stage(0, 0);

#pragma unroll 1
  for (int kb = 0; kb < 4; ++kb) {
    int cur = kb & 1;
    __syncthreads();                    // tile kb DMA drained; prev-buf readers done
    if (kb < 3) stage(kb + 1, cur ^ 1); // in flight during compute
    const unsigned short* As = (const unsigned short*)(smem + cur * 16384);
    const unsigned short* Bs = (const unsigned short*)(smem + 32768 + cur * 16384);
#pragma unroll
    for (int kk = 0; kk < 2; ++kk) {
      bf16x8 af[4], bfr[4];
      int sw = ((kk * 4 + quad) ^ (l16 & 7)) * 8;
#pragma unroll
      for (int m = 0; m < 4; ++m)
        af[m] = *(const bf16x8*)&As[(wr * 64 + m * 16 + l16) * 64 + sw];
#pragma unroll
      for (int n = 0; n < 4; ++n)
        bfr[n] = *(const bf16x8*)&Bs[(wc * 64 + n * 16 + l16) * 64 + sw];
#pragma unroll
      for (int m = 0; m < 4; ++m)
#pragma unroll
        for (int n = 0; n < 4; ++n)
          acc[m][n] = __builtin_amdgcn_mfma_f32_16x16x32_bf16(af[m], bfr[n], acc[m][n], 0, 0, 0);
    }
  }

#pragma unroll
  for (int m = 0; m < 4; ++m)
#pragma unroll
    for (int n = 0; n < 4; ++n)
#pragma unroll
      for (int r = 0; r < 4; ++r) {
        int row = m0 + wr * 64 + m * 16 + quad * 4 + r;
        int col = n0 + wc * 64 + n * 16 + l16;
        Cb[(size_t)row * ldc + col] = f2bf(acc[m][n][r]);
      }
}

// ---------------- fused attention (v8, proven 89 us): waves = (iq x jh), zero duplication ----
__global__ __launch_bounds__(512, 2) void attn(const unsigned short* __restrict__ qk,   // [B][N][512] (q|k)
                                               const unsigned short* __restrict__ vbuf, // [B][C][N]
                                               unsigned short* __restrict__ opart0,     // [B][N][C] bf16 (kh=0)
                                               unsigned short* __restrict__ opart1,     // [B][N][C] bf16 (kh=1)
                                               float* __restrict__ lpart) {             // [B*2][N]
  __shared__ __attribute__((aligned(16))) char smem[131072]; // K0|K1|V0|V1, 32 KB each

  int xcd = blockIdx.x & 7, slot = blockIdx.x >> 3;
  int b = xcd >> 1;
  int kh = xcd & 1;
  int i0 = slot * 128;
  int k0 = kh * 32;

  int t = threadIdx.x, w = t >> 6, l = t & 63;
  int l31 = l & 31, hi = l >> 5;
  int jh = w & 1;            // j-half
  int iq = w >> 1;           // i-quarter

  const size_t bqk = (size_t)b * NN * 512;
  const size_t bv = (size_t)b * CC * NN;

  auto stage = [&](int tile, int buf) {
    const unsigned short* kg = qk + bqk + (size_t)tile * 64 * 512 + 256;
    char* kb = smem + buf * 32768;
#pragma unroll
    for (int it = 0; it < 4; ++it) {
      int pp = w * 4 + it;                    // instr-block 0..31 (2 rows each)
      int r = 2 * pp + (l >> 5);
      int c = (l & 31) ^ (r & 31);
      async16(kg + (size_t)r * 512 + c * 8, kb + pp * 1024);
    }
    const unsigned short* vg = vbuf + bv + (size_t)tile * 64;
    char* vb = smem + 65536 + buf * 32768;
    int cj = (l & 7) ^ ((l >> 3) & 7);
#pragma unroll
    for (int it = 0; it < 4; ++it) {
      int pp = w * 4 + it;                    // instr-block 0..31 (8 c-rows each)
      int rc = 8 * pp + (l >> 3);
      async16(vg + (size_t)rc * NN + cj * 8, vb + pp * 1024);
    }
  };

  stage(k0, 0);

  // Q fragments (B-operand): lane = i = i0 + iq*32 + l31, elems c = ks*16 + hi*8 + 0..7
  bf16x8 qreg[16];
  {
    const unsigned short* qp = qk + bqk + (size_t)(i0 + iq * 32 + l31) * 512 + hi * 8;
#pragma unroll
    for (int ks = 0; ks < 16; ++ks)
      qreg[ks] = *(const bf16x8*)(qp + ks * 16);
  }

  floatx16 oacc[8];
#pragma unroll
  for (int cf = 0; cf < 8; ++cf)
#pragma unroll
    for (int r = 0; r < 16; ++r) oacc[cf][r] = 0.f;
  float lacc = 0.f;

  for (int kt = 0; kt < 32; ++kt) {
    int cur = kt & 1;
    __syncthreads();                      // tile kt DMA drained; all waves past prev buf reads
    if (kt < 31) stage(k0 + kt + 1, cur ^ 1);   // in flight during compute below

    const unsigned short* Kc = (const unsigned short*)(smem + cur * 32768);
    const unsigned short* Vc = (const unsigned short*)(smem + 65536 + cur * 32768);

    // S^T = K . Q^T for own j-half (D[m=j][n=i]; lane = i)
    floatx16 st;
#pragma unroll
    for (int r = 0; r < 16; ++r) st[r] = 0.f;
#pragma unroll
    for (int ks = 0; ks < 16; ++ks) {
      bf16x8 kf = *(const bf16x8*)&Kc[(jh * 32 + l31) * 256 + (((ks << 1) | hi) ^ l31) * 8];
      st = __builtin_amdgcn_mfma_f32_32x32x16_bf16(kf, qreg[ks], st, 0, 0, 0);
    }

    // P = exp2(S^T); pack bf16 pairs along j
    u32 pr[8];
#pragma unroll
    for (int k2 = 0; k2 < 8; ++k2) {
      float p0 = __builtin_amdgcn_exp2f(st[2 * k2]);
      float p1 = __builtin_amdgcn_exp2f(st[2 * k2 + 1]);
      lacc += p0 + p1;
      pr[k2] = __builtin_amdgcn_perm(fbits(p1), fbits(p0), 0x07060302u);
    }

    // rearrange into PV A-fragments (elems j = jh*32 + s*16 + hi*8 + 0..7) via hi-half exchange
    union U { u32 u[4]; bf16x8 v; } a0, a1;
    {
      u32 sA = hi ? pr[0] : pr[2], sB = hi ? pr[1] : pr[3];
      u32 rA = (u32)__shfl_xor((int)sA, 32, 64);
      u32 rB = (u32)__shfl_xor((int)sB, 32, 64);
      a0.u[0] = hi ? rA : pr[0]; a0.u[1] = hi ? rB : pr[1];
      a0.u[2] = hi ? pr[2] : rA; a0.u[3] = hi ? pr[3] : rB;
      sA = hi ? pr[4] : pr[6]; sB = hi ? pr[5] : pr[7];
      rA = (u32)__shfl_xor((int)sA, 32, 64);
      rB = (u32)__shfl_xor((int)sB, 32, 64);
      a1.u[0] = hi ? rA : pr[4]; a1.u[1] = hi ? rB : pr[5];
      a1.u[2] = hi ? pr[6] : rA; a1.u[3] = hi ? pr[7] : rB;
    }

    // O_partial += P . V over own j-half; full 256 c (B-frag: lane = c = cf*32+l31, elems = j)
#pragma unroll
    for (int cf = 0; cf < 8; ++cf) {
      const unsigned short* vrow = Vc + (cf * 32 + l31) * 64;
      bf16x8 v0 = *(const bf16x8*)(vrow + (((jh * 4) | hi) ^ (l31 & 7)) * 8);
      oacc[cf] = __builtin_amdgcn_mfma_f32_32x32x16_bf16(a0.v, v0, oacc[cf], 0, 0, 0);
      bf16x8 v1 = *(const bf16x8*)(vrow + (((jh * 4 + 2) | hi) ^ (l31 & 7)) * 8);
      oacc[cf] = __builtin_amdgcn_mfma_f32_32x32x16_bf16(a1.v, v1, oacc[cf], 0, 0, 0);
    }
  }

  // ---- epilogue: combine jh pairs. Phase A: O via LDS overlay (dead K/V buffers).
  float l2 = lacc + __shfl_xor(lacc, 32, 64);   // per-lane i = iq*32+l31, own j-half complete

  float* Of = (float*)smem + iq * 8192;         // [32 i][256 c] fp32 per iq (32 KB each)
  __syncthreads();
  if (jh == 1) {
#pragma unroll
    for (int cf = 0; cf < 8; ++cf)
#pragma unroll
      for (int r = 0; r < 16; ++r) {
        int il = (r & 3) + 8 * (r >> 2) + 4 * hi;
        Of[il * 256 + cf * 32 + l31] = oacc[cf][r];
      }
  }
  __syncthreads();
  unsigned short* ops = kh ? opart1 : opart0;
  size_t rowbase = (size_t)b * NN + i0 + iq * 32;
  if (jh == 0) {
#pragma unroll
    for (int cf = 0; cf < 8; ++cf)
#pragma unroll
      for (int r = 0; r < 16; ++r) {
        int il = (r & 3) + 8 * (r >> 2) + 4 * hi;
        float v = oacc[cf][r] + Of[il * 256 + cf * 32 + l31];
        ops[(rowbase + il) * CC + cf * 32 + l31] = f2bf(v);
      }
  }
  __syncthreads();
  // Phase B: l via small LDS pass
  float* Lred = (float*)smem;                   // [8 waves][32]
  if (hi == 0) Lred[w * 32 + l31] = l2;
  __syncthreads();
  if (jh == 0 && hi == 0) {
    size_t pbl = (size_t)(b * 2 + kh) * NN + i0;
    lpart[pbl + iq * 32 + l31] = Lred[(iq * 2) * 32 + l31] + Lred[(iq * 2 + 1) * 32 + l31];
  }
}

// ------- proj GEMM v2: 128x64 tiles, 512 blocks (2/CU), DMA-A dbuf, pipelined B combine -----
// out[b][co][n] = sum_c wp[co][c] * ((op0[b][n][c]+op1[b][n][c]) / (l0+l1)[b][n]) + x[b][co][n]
__global__ __launch_bounds__(256, 2) void gemm_proj(const unsigned short* __restrict__ wp,
                                                    const unsigned short* __restrict__ op0,
                                                    const unsigned short* __restrict__ op1,
                                                    const float* __restrict__ lp,
                                                    float* __restrict__ out, const float* __restrict__ x) {
  __shared__ __attribute__((aligned(16))) char smem[51456];
  // [0,32768): A0|A1 (128x64 swizzled, 16 KB each); [32768,51200): B0|B1 ([64][72] padded,
  // 9216 B each); [51200,51456): Linv[64]
  int mt = blockIdx.x & 1;          // co-half
  int nt = blockIdx.x >> 1;         // 64 n-tiles of 64
  int b = blockIdx.y;
  int m0 = mt * 128, n0 = nt * 64;
  int t = threadIdx.x, w = t >> 6, l = t & 63;
  int l16 = l & 15, quad = l >> 4;
  int wr = w >> 1, wc = w & 1;
  const unsigned short* Ab = wp + (size_t)m0 * 256;
  float* Linv = (float*)(smem + 51200);

  auto stageA = [&](int kb, int buf) {
    int rsub = l >> 3;
    int cj = (l & 7) ^ rsub;
    char* ab = smem + buf * 16384;
#pragma unroll
    for (int it = 0; it < 4; ++it) {
      int pp = w * 4 + it;
      size_t go = (size_t)(8 * pp + rsub) * 256 + kb * 64 + cj * 8;
      async16(Ab + go, ab + pp * 1024);
    }
  };

  int brow = t >> 2;                 // 64 rows, 4 threads/row
  int bck = (t & 3) * 16;            // 16-elem chunk within the 64-elem K-slab
  size_t bgo_base = ((size_t)b * NN + n0 + brow) * 256 + bck;
  uint4 b0a, b0b, b1a, b1b;
  auto loadB = [&](int kb) {
    size_t go = bgo_base + kb * 64;
    b0a = *(const uint4*)(op0 + go);
    b0b = *(const uint4*)(op0 + go + 8);
    b1a = *(const uint4*)(op1 + go);
    b1b = *(const uint4*)(op1 + go + 8);
  };

  if (t < 64) Linv[t] = 1.f / (lp[b * 8192 + n0 + t] + lp[b * 8192 + 4096 + n0 + t]);
  stageA(0, 0);
  loadB(0);
  __syncthreads();                   // Linv visible

  floatx4 acc[4][2];
#pragma unroll
  for (int m = 0; m < 4; ++m)
#pragma unroll
    for (int n = 0; n < 2; ++n)
#pragma unroll
      for (int r = 0; r < 4; ++r) acc[m][n][r] = 0.f;

#pragma unroll 1
  for (int kb = 0; kb < 4; ++kb) {
    int cur = kb & 1;
    // combine+write B[kb] into Bs[cur] (last readers of Bs[cur] were kb-2, behind a barrier)
    {
      float li = Linv[brow];
      unsigned short* Bs = (unsigned short*)(smem + 32768 + cur * 9216);
      const unsigned short* pa = (const unsigned short*)&b0a;
      const unsigned short* pc = (const unsigned short*)&b1a;
      union { unsigned short us[8]; uint4 q; } o1_, o2_;
#pragma unroll
      for (int j = 0; j < 8; ++j) o1_.us[j] = f2bf((bf2f(pa[j]) + bf2f(pc[j])) * li);
      pa = (const unsigned short*)&b0b;
      pc = (const unsigned short*)&b1b;
#pragma unroll
      for (int j = 0; j < 8; ++j) o2_.us[j] = f2bf((bf2f(pa[j]) + bf2f(pc[j])) * li);
      *(uint4*)&Bs[brow * 72 + bck] = o1_.q;
      *(uint4*)&Bs[brow * 72 + bck + 8] = o2_.q;
    }
    if (kb < 3) loadB(kb + 1);       // global loads in flight across the barrier
    __syncthreads();                 // A-DMA kb drained; B writes visible
    if (kb < 3) stageA(kb + 1, cur ^ 1);
    const unsigned short* As = (const unsigned short*)(smem + cur * 16384);
    const unsigned short* Bs = (const unsigned short*)(smem + 32768 + cur * 9216);
#pragma unroll
    for (int kk = 0; kk < 2; ++kk) {
      bf16x8 af[4], bfr[2];
      int sw = ((kk * 4 + quad) ^ (l16 & 7)) * 8;
#pragma unroll
      for (int m = 0; m < 4; ++m)
        af[m] = *(const bf16x8*)&As[(wr * 64 + m * 16 + l16) * 64 + sw];
#pragma unroll
      for (int n = 0; n < 2; ++n)
        bfr[n] = *(const bf16x8*)&Bs[(wc * 32 + n * 16 + l16) * 72 + kk * 32 + quad * 8];
#pragma unroll
      for (int m = 0; m < 4; ++m)
#pragma unroll
        for (int n = 0; n < 2; ++n)
          acc[m][n] = __builtin_amdgcn_mfma_f32_16x16x32_bf16(af[m], bfr[n], acc[m][n], 0, 0, 0);
    }
  }

  size_t cb = (size_t)b * CC * NN;
#pragma unroll
  for (int m = 0; m < 4; ++m)
#pragma unroll
    for (int n = 0; n < 2; ++n)
#pragma unroll
      for (int r = 0; r < 4; ++r) {
        int row = m0 + wr * 64 + m * 16 + quad * 4 + r;
        int col = n0 + wc * 32 + n * 16 + l16;
        size_t idx = cb + (size_t)row * NN + col;
        out[idx] = acc[m][n][r] + x[idx];
      }
}

extern "C" void kernel_launch(void* const* d_in, const int* in_sizes, int n_in,
                              void* d_out, int out_size, void* d_ws, size_t ws_size,
                              hipStream_t stream) {
  const float* x     = (const float*)d_in[0];
  // d_in[1] = t (unused)
  const float* gamma = (const float*)d_in[2];
  const float* beta  = (const float*)d_in[3];
  const float* wqkv  = (const float*)d_in[4];
  const float* wproj = (const float*)d_in[5];
  float* out = (float*)d_out;

  // Workspace layout (max 42,468,352 B — proven footprint):
  //   [0,1024)            mr (dead after gn_apply)
  //   [1024, 394240)      wq_bf 384 KB (dead after qkv/v GEMM) — lpart overlays @1024
  //   [394240, 525312)    wp_bf 128 KB (live until proj GEMM)
  //   [525312, 8913920)   normed 8 MB (dead after qkv/v GEMM) — opart0 overlays
  //   [8913920, 25691136) qkbuf 16 MB (dead after attn)
  //   [25691136,34079744) vbuf 8 MB
  //   [34079744,42468352) opart1 8 MB
  char* p = (char*)d_ws;
  float* mr               = (float*)(p + 0);
  unsigned short* wq_bf   = (unsigned short*)(p + 1024);
  unsigned short* wp_bf   = (unsigned short*)(p + 394240);
  unsigned short* normed  = (unsigned short*)(p + 525312);
  unsigned short* qkbuf   = (unsigned short*)(p + 8913920);
  unsigned short* vbuf    = (unsigned short*)(p + 25691136);
  unsigned short* opart1  = (unsigned short*)(p + 34079744);
  unsigned short* opart0  = normed;                            // overlay (normed dead after GEMMs)
  float* lpart            = (float*)(p + 1024);                // overlay (wq_bf dead after GEMMs)
  unsigned short* wv_bf   = wq_bf + 512 * 256;

  gn_stats_wconv<<<1152, 256, 0, stream>>>(x, mr, wqkv, wproj, wq_bf, wp_bf);
  gn_apply<<<1024, 256, 0, stream>>>(x, mr, gamma, beta, normed);
  gemm_qkv_v<<<dim3(192, 4), 256, 0, stream>>>(normed, wq_bf, wv_bf, qkbuf, vbuf);
  attn<<<256, 512, 0, stream>>>(qkbuf, vbuf, opart0, opart1, lpart);
  gemm_proj<<<dim3(128, 4), 256, 0, stream>>>(wp_bf, opart0, opart1, lpart, out, x);
}